// Round 4
// baseline (238.237 us; speedup 1.0000x reference)
//
#include <hip/hip_runtime.h>

#define BATCH 2048
#define DIM   1024
#define SPC   8
#define BM    128
#define BN    64
#define BK    32
#define NKT   (DIM / BK)   // 32

typedef _Float16 half8  __attribute__((ext_vector_type(8)));
typedef _Float16 half4v __attribute__((ext_vector_type(4)));
typedef float    f32x4  __attribute__((ext_vector_type(4)));

constexpr float INV_T    = 1.0f / 0.01f;
constexpr float LO_SCALE = 2048.0f;        // 2^11, exact
constexpr float INV_LO   = 1.0f / 2048.0f;

__device__ __forceinline__ float sig_main(float x) {
  // faithful: e = clip(-x/0.01, -50, 50); 1/(1+exp(e))
  float e = -x * INV_T;
  e = fminf(fmaxf(e, -50.0f), 50.0f);
  return 1.0f / (1.0f + __expf(e));
}

__device__ __forceinline__ void gl_lds16(const _Float16* g, _Float16* l) {
  __builtin_amdgcn_global_load_lds((const __attribute__((address_space(1))) void*)g,
                                   (__attribute__((address_space(3))) void*)l, 16, 0, 0);
}

// bank-conflict-free swizzle: slot(row,c) = row*4 + (c ^ ((row>>1)&3));
// applied identically on the gl_lds global SOURCE and on the ds_read (rule 21).
__device__ __forceinline__ int swz(int row, int c) { return row * 4 + (c ^ ((row >> 1) & 3)); }

// ---------------- kernel 0 (fused): fp32->fp16 hi/lo split  +  group sims ----------------
__global__ __launch_bounds__(256) void k_prep(const float* __restrict__ preds,
                                              _Float16* __restrict__ Ph,
                                              _Float16* __restrict__ Pl,
                                              float* __restrict__ G) {
  __shared__ float rows[SPC][DIM + 4];
  __shared__ float part[64][4];
  if (blockIdx.x < BATCH) {
    // ---- split: 2048 blocks x 256 thr x float4 = 2M floats ----
    const int i = blockIdx.x * 256 + threadIdx.x;
    const float4 x = ((const float4*)preds)[i];
    half4v h, l;
    h[0] = (_Float16)x.x; l[0] = (_Float16)((x.x - (float)h[0]) * LO_SCALE);
    h[1] = (_Float16)x.y; l[1] = (_Float16)((x.y - (float)h[1]) * LO_SCALE);
    h[2] = (_Float16)x.z; l[2] = (_Float16)((x.z - (float)h[2]) * LO_SCALE);
    h[3] = (_Float16)x.w; l[3] = (_Float16)((x.w - (float)h[3]) * LO_SCALE);
    ((half4v*)Ph)[i] = h;
    ((half4v*)Pl)[i] = l;
    return;
  }
  // ---- group sims: G[q][i] = <preds[q], preds[g*8+i]> in exact fp32 ----
  const int g = blockIdx.x - BATCH;
  const int tid = threadIdx.x;
  const float4* src = (const float4*)(preds + (size_t)g * SPC * DIM);
#pragma unroll
  for (int c = 0; c < 8; ++c) {
    int idx = c * 256 + tid;
    float4 v = src[idx];
    *(float4*)&rows[idx >> 8][(idx & 255) << 2] = v;
  }
  __syncthreads();
  const int p  = tid & 63;
  const int sl = tid >> 6;
  const float4* ra = (const float4*)&rows[p >> 3][sl * 256];
  const float4* rb = (const float4*)&rows[p & 7][sl * 256];
  float s = 0.0f;
#pragma unroll 8
  for (int e = 0; e < 64; ++e) {
    float4 a = ra[e], b = rb[e];
    s += a.x * b.x + a.y * b.y + a.z * b.z + a.w * b.w;
  }
  part[p][sl] = s;
  __syncthreads();
  if (tid < 64) {
    float v = part[tid][0] + part[tid][1] + part[tid][2] + part[tid][3];
    G[(size_t)(g * SPC + (tid >> 3)) * SPC + (tid & 7)] = v;
  }
}

// ---------------- kernel 1: MFMA split-fp16 S-tile GEMM + fused sigmoid-rank epilogue ----
// S = Ah*Bh + (Ah*Bl' + Al'*Bh)/2048 (P @ P^T), 128x64 tiles, 512 blocks (2/CU).
__global__ __launch_bounds__(256, 2) void k_main(const _Float16* __restrict__ Ph,
                                                 const _Float16* __restrict__ Pl,
                                                 const float* __restrict__ G,
                                                 float* __restrict__ rk_sum) {
  // statically-disjoint double buffers: compiler can prove STAGE(buf1) !alias ds_read(buf0)
  __shared__ __align__(16) _Float16 sAh0[BM * BK], sAl0[BM * BK], sBh0[BN * BK], sBl0[BN * BK];
  __shared__ __align__(16) _Float16 sAh1[BM * BK], sAl1[BM * BK], sBh1[BN * BK], sBl1[BN * BK];
  const int t    = threadIdx.x;
  const int lane = t & 63;
  const int w    = t >> 6;
  const int wr   = w >> 1, wc = w & 1;       // 2x2 wave grid: wave tile 64x32

  // XCD-aware bijective swizzle (nwg=512, 512%8==0)
  int bid = blockIdx.y * gridDim.x + blockIdx.x;
  bid = (bid & 7) * (512 / 8) + (bid >> 3);
  const int qb = (bid / 32) * BM;            // 16 q-tiles
  const int jb = (bid % 32) * BN;            // 32 j-tiles

  f32x4 accH[4][2], accX[4][2];
#pragma unroll
  for (int m = 0; m < 4; ++m)
#pragma unroll
    for (int n = 0; n < 2; ++n) {
      accH[m][n] = (f32x4){0.f, 0.f, 0.f, 0.f};
      accX[m][n] = (f32x4){0.f, 0.f, 0.f, 0.f};
    }

  // 6 gl_lds16 per thread per K-step (A: 2x h,l ; B: 1x h,l), LDS dest linear,
  // global source pre-swizzled so the swizzled ds_read sees correct data.
  auto STAGE = [&](_Float16* dAh, _Float16* dAl, _Float16* dBh, _Float16* dBl, int kt) {
    const int kk = kt * BK;
#pragma unroll
    for (int e = 0; e < 2; ++e) {
      const int slot = e * 256 + t;
      const int row  = slot >> 2;
      const int c    = (slot & 3) ^ ((row >> 1) & 3);
      const size_t src = (size_t)(qb + row) * DIM + kk + c * 8;
      gl_lds16(Ph + src, dAh + (size_t)slot * 8);
      gl_lds16(Pl + src, dAl + (size_t)slot * 8);
    }
    {
      const int slot = t;
      const int row  = slot >> 2;
      const int c    = (slot & 3) ^ ((row >> 1) & 3);
      const size_t src = (size_t)(jb + row) * DIM + kk + c * 8;
      gl_lds16(Ph + src, dBh + (size_t)slot * 8);
      gl_lds16(Pl + src, dBl + (size_t)slot * 8);
    }
  };

  const int rl = lane & 15, ch = lane >> 4;
  auto COMPUTE = [&](const _Float16* bAh, const _Float16* bAl,
                     const _Float16* bBh, const _Float16* bBl) {
    half8 ah[4], al[4], bh[2], bl[2];
#pragma unroll
    for (int m = 0; m < 4; ++m) {
      const int r = wr * 64 + m * 16 + rl;
      const int s = swz(r, ch);
      ah[m] = *(const half8*)&bAh[(size_t)s * 8];
      al[m] = *(const half8*)&bAl[(size_t)s * 8];
    }
#pragma unroll
    for (int n = 0; n < 2; ++n) {
      const int r = wc * 32 + n * 16 + rl;
      const int s = swz(r, ch);
      bh[n] = *(const half8*)&bBh[(size_t)s * 8];
      bl[n] = *(const half8*)&bBl[(size_t)s * 8];
    }
#pragma unroll
    for (int m = 0; m < 4; ++m)
#pragma unroll
      for (int n = 0; n < 2; ++n) {
        accH[m][n] = __builtin_amdgcn_mfma_f32_16x16x32_f16(ah[m], bh[n], accH[m][n], 0, 0, 0);
        accX[m][n] = __builtin_amdgcn_mfma_f32_16x16x32_f16(ah[m], bl[n], accX[m][n], 0, 0, 0);
        accX[m][n] = __builtin_amdgcn_mfma_f32_16x16x32_f16(al[m], bh[n], accX[m][n], 0, 0, 0);
      }
  };

  STAGE(sAh0, sAl0, sBh0, sBl0, 0);
  __syncthreads();
#pragma unroll 1
  for (int kt = 0; kt < NKT; kt += 2) {
    if (kt + 1 < NKT) STAGE(sAh1, sAl1, sBh1, sBl1, kt + 1);  // prefetch overlaps compute
    COMPUTE(sAh0, sAl0, sBh0, sBl0);
    __syncthreads();                                          // drains vmcnt -> buf1 ready
    if (kt + 2 < NKT) STAGE(sAh0, sAl0, sBh0, sBl0, kt + 2);
    COMPUTE(sAh1, sAl1, sBh1, sBl1);
    __syncthreads();
  }

  // ---- fused epilogue; C/D layout (HW-verified): col=lane&15, row=(lane>>4)*4+reg ----
  const int colLane = lane & 15;
  const int rowLane = lane >> 4;
#pragma unroll
  for (int m = 0; m < 4; ++m) {
#pragma unroll
    for (int v = 0; v < 4; ++v) {
      const int q = qb + wr * 64 + m * 16 + rowLane * 4 + v;
      const float4 g0 = *(const float4*)&G[(size_t)q * 8];
      const float4 g1 = *(const float4*)&G[(size_t)q * 8 + 4];
      const float gv[8] = {g0.x, g0.y, g0.z, g0.w, g1.x, g1.y, g1.z, g1.w};
      const int qg = q >> 3;
      float sv[2];
      int jg[2], jp[2];
#pragma unroll
      for (int n = 0; n < 2; ++n) {
        sv[n] = accH[m][n][v] + accX[m][n][v] * INV_LO;
        const int j = jb + wc * 32 + n * 16 + colLane;
        jg[n] = j >> 3;
        jp[n] = j & 7;
      }
#pragma unroll
      for (int i = 0; i < 8; ++i) {
        float pr = 0.0f;
#pragma unroll
        for (int n = 0; n < 2; ++n) {
          float s = sig_main(sv[n] - gv[i]);
          if (jg[n] == qg && jp[n] == i) s = 0.0f;   // exact diag exclusion
          pr += s;
        }
        pr += __shfl_xor(pr, 1);
        pr += __shfl_xor(pr, 2);
        pr += __shfl_xor(pr, 4);
        pr += __shfl_xor(pr, 8);
        if (colLane == 0) atomicAdd(&rk_sum[(size_t)q * 8 + i], pr);
      }
    }
  }
}

// ---------------- kernel 2: rank -> recall -> scalar loss ----------------
__global__ __launch_bounds__(256) void k_fin(const float* __restrict__ rk_sum,
                                             float* __restrict__ out) {
  const int q = blockIdx.x * 256 + threadIdx.x;
  const float kv[5]  = {1.f, 2.f, 4.f, 8.f, 16.f};
  const float rkt[5] = {1.f, 0.5f, 0.25f, 0.125f, 0.0625f};
  const float nv[5]  = {1.f, 2.f, 4.f, 7.f, 7.f};
  const int r = q & 7;
  float vs[5] = {0.f, 0.f, 0.f, 0.f, 0.f};
#pragma unroll
  for (int i = 0; i < 8; ++i) {
    const float rk = 1.0f + rk_sum[(size_t)q * 8 + i];
    const bool self = (i == r);
#pragma unroll
    for (int k = 0; k < 5; ++k) {
      float e = (rk - kv[k]) * rkt[k];
      e = fminf(fmaxf(e, -50.0f), 50.0f);
      float v = 1.0f / (1.0f + __expf(e));
      vs[k] += self ? 0.0f : v;
    }
  }
  float rq = 0.0f;
#pragma unroll
  for (int k = 0; k < 5; ++k) rq += fminf(vs[k], kv[k]) / nv[k];
  float tv = (1.0f - rq * 0.2f) * (1.0f / (float)BATCH);
#pragma unroll
  for (int o = 1; o < 64; o <<= 1) tv += __shfl_xor(tv, o);
  if ((threadIdx.x & 63) == 0) atomicAdd(out, tv);
}

extern "C" void kernel_launch(void* const* d_in, const int* in_sizes, int n_in,
                              void* d_out, int out_size, void* d_ws, size_t ws_size,
                              hipStream_t stream) {
  const float* preds = (const float*)d_in[0];
  float* G      = (float*)d_ws;                               // 64 KB
  float* rk_sum = (float*)d_ws + (size_t)BATCH * SPC;         // 64 KB
  _Float16* Ph  = (_Float16*)((char*)d_ws + (128 << 10));     // 4 MB
  _Float16* Pl  = Ph + (size_t)BATCH * DIM;                   // 4 MB (ws >= 8.375 MB)
  hipMemsetAsync(rk_sum, 0, (size_t)BATCH * SPC * sizeof(float), stream);
  hipMemsetAsync(d_out, 0, sizeof(float), stream);
  k_prep<<<BATCH + BATCH / SPC, 256, 0, stream>>>(preds, Ph, Pl, G);
  k_main<<<dim3(BATCH / BN, BATCH / BM), 256, 0, stream>>>(Ph, Pl, G, rk_sum);
  k_fin<<<BATCH / 256, 256, 0, stream>>>(rk_sum, (float*)d_out);
}

// Round 5
// 130.959 us; speedup vs baseline: 1.8192x; 1.8192x over previous
//
#include <hip/hip_runtime.h>

#define BATCH 2048
#define DIM   1024
#define SPC   8
#define BM    128
#define BN    64
#define BK    32
#define NKT   (DIM / BK)   // 32
#define NJB   (BATCH / BN) // 32 j-blocks -> partial slices

typedef _Float16 half8  __attribute__((ext_vector_type(8)));
typedef _Float16 half4v __attribute__((ext_vector_type(4)));
typedef float    f32x4  __attribute__((ext_vector_type(4)));

constexpr float INV_T    = 1.0f / 0.01f;
constexpr float LO_SCALE = 2048.0f;        // 2^11, exact
constexpr float INV_LO   = 1.0f / 2048.0f;

__device__ __forceinline__ float sig_main(float x) {
  // faithful: e = clip(-x/0.01, -50, 50); 1/(1+exp(e))
  float e = -x * INV_T;
  e = fminf(fmaxf(e, -50.0f), 50.0f);
  return 1.0f / (1.0f + __expf(e));
}

__device__ __forceinline__ void gl_lds16(const _Float16* g, _Float16* l) {
  __builtin_amdgcn_global_load_lds((const __attribute__((address_space(1))) void*)g,
                                   (__attribute__((address_space(3))) void*)l, 16, 0, 0);
}

// bank-conflict-free swizzle: slot(row,c) = row*4 + (c ^ ((row>>1)&3));
// applied identically on the gl_lds global SOURCE and on the ds_read (rule 21).
__device__ __forceinline__ int swz(int row, int c) { return row * 4 + (c ^ ((row >> 1) & 3)); }

// ---------------- kernel 0 (fused): fp32->fp16 hi/lo split  +  group sims ----------------
__global__ __launch_bounds__(256) void k_prep(const float* __restrict__ preds,
                                              _Float16* __restrict__ Ph,
                                              _Float16* __restrict__ Pl,
                                              float* __restrict__ G) {
  __shared__ float rows[SPC][DIM + 4];
  __shared__ float part[64][4];
  if (blockIdx.x < BATCH) {
    const int i = blockIdx.x * 256 + threadIdx.x;
    const float4 x = ((const float4*)preds)[i];
    half4v h, l;
    h[0] = (_Float16)x.x; l[0] = (_Float16)((x.x - (float)h[0]) * LO_SCALE);
    h[1] = (_Float16)x.y; l[1] = (_Float16)((x.y - (float)h[1]) * LO_SCALE);
    h[2] = (_Float16)x.z; l[2] = (_Float16)((x.z - (float)h[2]) * LO_SCALE);
    h[3] = (_Float16)x.w; l[3] = (_Float16)((x.w - (float)h[3]) * LO_SCALE);
    ((half4v*)Ph)[i] = h;
    ((half4v*)Pl)[i] = l;
    return;
  }
  const int g = blockIdx.x - BATCH;
  const int tid = threadIdx.x;
  const float4* src = (const float4*)(preds + (size_t)g * SPC * DIM);
#pragma unroll
  for (int c = 0; c < 8; ++c) {
    int idx = c * 256 + tid;
    float4 v = src[idx];
    *(float4*)&rows[idx >> 8][(idx & 255) << 2] = v;
  }
  __syncthreads();
  const int p  = tid & 63;
  const int sl = tid >> 6;
  const float4* ra = (const float4*)&rows[p >> 3][sl * 256];
  const float4* rb = (const float4*)&rows[p & 7][sl * 256];
  float s = 0.0f;
#pragma unroll 8
  for (int e = 0; e < 64; ++e) {
    float4 a = ra[e], b = rb[e];
    s += a.x * b.x + a.y * b.y + a.z * b.z + a.w * b.w;
  }
  part[p][sl] = s;
  __syncthreads();
  if (tid < 64) {
    float v = part[tid][0] + part[tid][1] + part[tid][2] + part[tid][3];
    G[(size_t)(g * SPC + (tid >> 3)) * SPC + (tid & 7)] = v;
  }
}

// ---------------- kernel 1: MFMA split-fp16 S-tile GEMM + fused sigmoid-rank epilogue ----
// S = Ah*Bh + (Ah*Bl' + Al'*Bh)/2048 (P @ P^T), 128x64 tiles, 512 blocks (2/CU).
// NO global atomics: per-block partial written with one coalesced 4KB store.
__global__ __launch_bounds__(256, 2) void k_main(const _Float16* __restrict__ Ph,
                                                 const _Float16* __restrict__ Pl,
                                                 const float* __restrict__ G,
                                                 float* __restrict__ partial) {
  __shared__ __align__(16) _Float16 sAh0[BM * BK], sAl0[BM * BK], sBh0[BN * BK], sBl0[BN * BK];
  __shared__ __align__(16) _Float16 sAh1[BM * BK], sAl1[BM * BK], sBh1[BN * BK], sBl1[BN * BK];
  __shared__ float sRed[2][BM][SPC];         // 8KB: [wc][q_local][i]
  const int t    = threadIdx.x;
  const int lane = t & 63;
  const int w    = t >> 6;
  const int wr   = w >> 1, wc = w & 1;       // 2x2 wave grid: wave tile 64x32

  // XCD-aware bijective swizzle (nwg=512, 512%8==0)
  int bid = blockIdx.y * gridDim.x + blockIdx.x;
  bid = (bid & 7) * (512 / 8) + (bid >> 3);
  const int qb    = (bid / NJB) * BM;
  const int jbIdx = bid % NJB;
  const int jb    = jbIdx * BN;

  f32x4 accH[4][2], accX[4][2];
#pragma unroll
  for (int m = 0; m < 4; ++m)
#pragma unroll
    for (int n = 0; n < 2; ++n) {
      accH[m][n] = (f32x4){0.f, 0.f, 0.f, 0.f};
      accX[m][n] = (f32x4){0.f, 0.f, 0.f, 0.f};
    }

  auto STAGE = [&](_Float16* dAh, _Float16* dAl, _Float16* dBh, _Float16* dBl, int kt) {
    const int kk = kt * BK;
#pragma unroll
    for (int e = 0; e < 2; ++e) {
      const int slot = e * 256 + t;
      const int row  = slot >> 2;
      const int c    = (slot & 3) ^ ((row >> 1) & 3);
      const size_t src = (size_t)(qb + row) * DIM + kk + c * 8;
      gl_lds16(Ph + src, dAh + (size_t)slot * 8);
      gl_lds16(Pl + src, dAl + (size_t)slot * 8);
    }
    {
      const int slot = t;
      const int row  = slot >> 2;
      const int c    = (slot & 3) ^ ((row >> 1) & 3);
      const size_t src = (size_t)(jb + row) * DIM + kk + c * 8;
      gl_lds16(Ph + src, dBh + (size_t)slot * 8);
      gl_lds16(Pl + src, dBl + (size_t)slot * 8);
    }
  };

  const int rl = lane & 15, ch = lane >> 4;
  auto COMPUTE = [&](const _Float16* bAh, const _Float16* bAl,
                     const _Float16* bBh, const _Float16* bBl) {
    half8 ah[4], al[4], bh[2], bl[2];
#pragma unroll
    for (int m = 0; m < 4; ++m) {
      const int r = wr * 64 + m * 16 + rl;
      const int s = swz(r, ch);
      ah[m] = *(const half8*)&bAh[(size_t)s * 8];
      al[m] = *(const half8*)&bAl[(size_t)s * 8];
    }
#pragma unroll
    for (int n = 0; n < 2; ++n) {
      const int r = wc * 32 + n * 16 + rl;
      const int s = swz(r, ch);
      bh[n] = *(const half8*)&bBh[(size_t)s * 8];
      bl[n] = *(const half8*)&bBl[(size_t)s * 8];
    }
#pragma unroll
    for (int m = 0; m < 4; ++m)
#pragma unroll
      for (int n = 0; n < 2; ++n) {
        accH[m][n] = __builtin_amdgcn_mfma_f32_16x16x32_f16(ah[m], bh[n], accH[m][n], 0, 0, 0);
        accX[m][n] = __builtin_amdgcn_mfma_f32_16x16x32_f16(ah[m], bl[n], accX[m][n], 0, 0, 0);
        accX[m][n] = __builtin_amdgcn_mfma_f32_16x16x32_f16(al[m], bh[n], accX[m][n], 0, 0, 0);
      }
  };

  STAGE(sAh0, sAl0, sBh0, sBl0, 0);
  __syncthreads();
#pragma unroll 1
  for (int kt = 0; kt < NKT; kt += 2) {
    if (kt + 1 < NKT) STAGE(sAh1, sAl1, sBh1, sBl1, kt + 1);
    COMPUTE(sAh0, sAl0, sBh0, sBl0);
    __syncthreads();
    if (kt + 2 < NKT) STAGE(sAh0, sAl0, sBh0, sBl0, kt + 2);
    COMPUTE(sAh1, sAl1, sBh1, sBl1);
    __syncthreads();
  }

  // ---- fused epilogue; C/D layout (HW-verified): col=lane&15, row=(lane>>4)*4+reg ----
  const int colLane = lane & 15;
  const int rowLane = lane >> 4;
#pragma unroll
  for (int m = 0; m < 4; ++m) {
#pragma unroll
    for (int v = 0; v < 4; ++v) {
      const int q = qb + wr * 64 + m * 16 + rowLane * 4 + v;
      const float4 g0 = *(const float4*)&G[(size_t)q * 8];
      const float4 g1 = *(const float4*)&G[(size_t)q * 8 + 4];
      const float gv[8] = {g0.x, g0.y, g0.z, g0.w, g1.x, g1.y, g1.z, g1.w};
      const int qg = q >> 3;
      float sv[2];
      int jg[2], jp[2];
#pragma unroll
      for (int n = 0; n < 2; ++n) {
        sv[n] = accH[m][n][v] + accX[m][n][v] * INV_LO;
        const int j = jb + wc * 32 + n * 16 + colLane;
        jg[n] = j >> 3;
        jp[n] = j & 7;
      }
#pragma unroll
      for (int i = 0; i < 8; ++i) {
        float pr = 0.0f;
#pragma unroll
        for (int n = 0; n < 2; ++n) {
          float s = sig_main(sv[n] - gv[i]);
          if (jg[n] == qg && jp[n] == i) s = 0.0f;   // exact diag exclusion
          pr += s;
        }
        pr += __shfl_xor(pr, 1);
        pr += __shfl_xor(pr, 2);
        pr += __shfl_xor(pr, 4);
        pr += __shfl_xor(pr, 8);
        if (colLane == 0)
          sRed[wc][wr * 64 + m * 16 + rowLane * 4 + v][i] = pr;   // LDS, no global atomic
      }
    }
  }
  __syncthreads();
  // cooperative combine of the two j-halves + ONE coalesced 4KB store per block
  {
    const float* r0 = &sRed[0][0][0];
    const float* r1 = &sRed[1][0][0];
    float4 a = *(const float4*)&r0[t * 4];
    float4 b = *(const float4*)&r1[t * 4];
    float4 s = {a.x + b.x, a.y + b.y, a.z + b.z, a.w + b.w};
    *(float4*)&partial[((size_t)jbIdx * BATCH + qb) * SPC + t * 4] = s;
  }
}

// ---------------- kernel 2: reduce partials -> rank -> recall -> scalar loss ----------------
__global__ __launch_bounds__(256) void k_fin(const float* __restrict__ partial,
                                             float* __restrict__ out) {
  const int q = blockIdx.x * 256 + threadIdx.x;
  float rk8[8] = {0.f, 0.f, 0.f, 0.f, 0.f, 0.f, 0.f, 0.f};
#pragma unroll 4
  for (int p = 0; p < NJB; ++p) {
    const float* base = &partial[((size_t)p * BATCH + q) * SPC];
    float4 a = *(const float4*)&base[0];
    float4 b = *(const float4*)&base[4];
    rk8[0] += a.x; rk8[1] += a.y; rk8[2] += a.z; rk8[3] += a.w;
    rk8[4] += b.x; rk8[5] += b.y; rk8[6] += b.z; rk8[7] += b.w;
  }
  const float kv[5]  = {1.f, 2.f, 4.f, 8.f, 16.f};
  const float rkt[5] = {1.f, 0.5f, 0.25f, 0.125f, 0.0625f};
  const float nv[5]  = {1.f, 2.f, 4.f, 7.f, 7.f};
  const int r = q & 7;
  float vs[5] = {0.f, 0.f, 0.f, 0.f, 0.f};
#pragma unroll
  for (int i = 0; i < 8; ++i) {
    const float rk = 1.0f + rk8[i];
    const bool self = (i == r);
#pragma unroll
    for (int k = 0; k < 5; ++k) {
      float e = (rk - kv[k]) * rkt[k];
      e = fminf(fmaxf(e, -50.0f), 50.0f);
      float v = 1.0f / (1.0f + __expf(e));
      vs[k] += self ? 0.0f : v;
    }
  }
  float rq = 0.0f;
#pragma unroll
  for (int k = 0; k < 5; ++k) rq += fminf(vs[k], kv[k]) / nv[k];
  float tv = (1.0f - rq * 0.2f) * (1.0f / (float)BATCH);
#pragma unroll
  for (int o = 1; o < 64; o <<= 1) tv += __shfl_xor(tv, o);
  if ((threadIdx.x & 63) == 0) atomicAdd(out, tv);
}

extern "C" void kernel_launch(void* const* d_in, const int* in_sizes, int n_in,
                              void* d_out, int out_size, void* d_ws, size_t ws_size,
                              hipStream_t stream) {
  const float* preds = (const float*)d_in[0];
  float* G       = (float*)d_ws;                                   // 64 KB
  float* partial = (float*)((char*)d_ws + (64 << 10));             // 2 MB  [NJB][BATCH][SPC]
  _Float16* Ph   = (_Float16*)((char*)d_ws + (64 << 10) + (2 << 20)); // 4 MB
  _Float16* Pl   = Ph + (size_t)BATCH * DIM;                       // 4 MB (ws >= ~10.1 MB)
  hipMemsetAsync(d_out, 0, sizeof(float), stream);
  k_prep<<<BATCH + BATCH / SPC, 256, 0, stream>>>(preds, Ph, Pl, G);
  k_main<<<dim3(BATCH / BN, BATCH / BM), 256, 0, stream>>>(Ph, Pl, G, partial);
  k_fin<<<BATCH / 256, 256, 0, stream>>>(partial, (float*)d_out);
}

// Round 8
// 121.599 us; speedup vs baseline: 1.9592x; 1.0770x over previous
//
#include <hip/hip_runtime.h>

#define BATCH 2048
#define DIM   1024
#define SPC   8
#define BM    64
#define BN    64
#define BK    32
#define NKT   (DIM / BK)   // 32
#define NJB   (BATCH / BN) // 32 j-blocks -> partial slices

typedef _Float16 half8  __attribute__((ext_vector_type(8)));
typedef _Float16 half4v __attribute__((ext_vector_type(4)));
typedef float    f32x4  __attribute__((ext_vector_type(4)));

constexpr float INV_T    = 1.0f / 0.01f;
constexpr float LO_SCALE = 2048.0f;        // 2^11, exact
constexpr float INV_LO   = 1.0f / 2048.0f;

__device__ __forceinline__ float sig_fast(float x) {
  // e = clip(-x/0.01, -50, 50); 1/(1+exp(e)) with v_rcp (~1e-7 err, far under tol)
  float e = fminf(fmaxf(-x * INV_T, -50.0f), 50.0f);
  return __builtin_amdgcn_rcpf(1.0f + __expf(e));
}

__device__ __forceinline__ void gl_lds16(const _Float16* g, _Float16* l) {
  __builtin_amdgcn_global_load_lds((const __attribute__((address_space(1))) void*)g,
                                   (__attribute__((address_space(3))) void*)l, 16, 0, 0);
}

// bank-conflict-free swizzle (verified R5: SQ_LDS_BANK_CONFLICT ~0):
// slot(row,c) = row*4 + (c ^ ((row>>1)&3)); applied on gl_lds global SOURCE and ds_read (rule 21).
__device__ __forceinline__ int swz(int row, int c) { return row * 4 + (c ^ ((row >> 1) & 3)); }

// ---------------- kernel 0 (fused): fp32->fp16 hi/lo split  +  group sims ----------------
__global__ __launch_bounds__(256) void k_prep(const float* __restrict__ preds,
                                              _Float16* __restrict__ Ph,
                                              _Float16* __restrict__ Pl,
                                              float* __restrict__ G) {
  __shared__ float rows[SPC][DIM + 4];
  __shared__ float part[64][4];
  if (blockIdx.x < BATCH) {
    const int i = blockIdx.x * 256 + threadIdx.x;
    const float4 x = ((const float4*)preds)[i];
    half4v h, l;
    h[0] = (_Float16)x.x; l[0] = (_Float16)((x.x - (float)h[0]) * LO_SCALE);
    h[1] = (_Float16)x.y; l[1] = (_Float16)((x.y - (float)h[1]) * LO_SCALE);
    h[2] = (_Float16)x.z; l[2] = (_Float16)((x.z - (float)h[2]) * LO_SCALE);
    h[3] = (_Float16)x.w; l[3] = (_Float16)((x.w - (float)h[3]) * LO_SCALE);
    ((half4v*)Ph)[i] = h;
    ((half4v*)Pl)[i] = l;
    return;
  }
  const int g = blockIdx.x - BATCH;
  const int tid = threadIdx.x;
  const float4* src = (const float4*)(preds + (size_t)g * SPC * DIM);
#pragma unroll
  for (int c = 0; c < 8; ++c) {
    int idx = c * 256 + tid;
    float4 v = src[idx];
    *(float4*)&rows[idx >> 8][(idx & 255) << 2] = v;
  }
  __syncthreads();
  const int p  = tid & 63;
  const int sl = tid >> 6;
  const float4* ra = (const float4*)&rows[p >> 3][sl * 256];
  const float4* rb = (const float4*)&rows[p & 7][sl * 256];
  float s = 0.0f;
#pragma unroll 8
  for (int e = 0; e < 64; ++e) {
    float4 a = ra[e], b = rb[e];
    s += a.x * b.x + a.y * b.y + a.z * b.z + a.w * b.w;
  }
  part[p][sl] = s;
  __syncthreads();
  if (tid < 64) {
    float v = part[tid][0] + part[tid][1] + part[tid][2] + part[tid][3];
    G[(size_t)(g * SPC + (tid >> 3)) * SPC + (tid & 7)] = v;
  }
}

// ---------------- kernel 1: MFMA split-fp16 S-tile GEMM + fused sigmoid-rank epilogue ----
// 64x64 tiles, 1024 blocks (4/CU, 16 waves/CU). S = Ah*Bh + (Ah*Bl' + Al'*Bh)/2048.
__global__ __launch_bounds__(256, 4) void k_main(const _Float16* __restrict__ Ph,
                                                 const _Float16* __restrict__ Pl,
                                                 const float* __restrict__ G,
                                                 float* __restrict__ partial) {
  __shared__ __align__(16) _Float16 sAh0[BM * BK], sAl0[BM * BK], sBh0[BN * BK], sBl0[BN * BK];
  __shared__ __align__(16) _Float16 sAh1[BM * BK], sAl1[BM * BK], sBh1[BN * BK], sBl1[BN * BK];
  __shared__ float sRed[2][BM][SPC];         // 4KB  -> total LDS 36KB -> 4 blocks/CU
  const int t    = threadIdx.x;
  const int lane = t & 63;
  const int w    = t >> 6;
  const int wr   = w >> 1, wc = w & 1;       // 2x2 wave grid: wave tile 32x32

  // XCD mapping: xcd = dispatch&7 owns j-tiles [xcd*4, xcd*4+4) -> B-panel (1MB) L2-resident
  const int d    = blockIdx.y * 32 + blockIdx.x;
  const int xcd  = d & 7, idx = d >> 3;
  const int jbIdx = xcd * 4 + (idx & 3);
  const int qb    = (idx >> 2) * BM;
  const int jb    = jbIdx * BN;

  f32x4 accH[2][2], accX[2][2];
#pragma unroll
  for (int m = 0; m < 2; ++m)
#pragma unroll
    for (int n = 0; n < 2; ++n) {
      accH[m][n] = (f32x4){0.f, 0.f, 0.f, 0.f};
      accX[m][n] = (f32x4){0.f, 0.f, 0.f, 0.f};
    }

  // 4 gl_lds16 per thread per K-step; LDS dest linear, global source pre-swizzled.
  auto STAGE = [&](_Float16* dAh, _Float16* dAl, _Float16* dBh, _Float16* dBl, int kt) {
    const int kk  = kt * BK;
    const int row = t >> 2;
    const int c   = (t & 3) ^ ((row >> 1) & 3);
    const size_t sA = (size_t)(qb + row) * DIM + kk + c * 8;
    const size_t sB = (size_t)(jb + row) * DIM + kk + c * 8;
    gl_lds16(Ph + sA, dAh + (size_t)t * 8);
    gl_lds16(Pl + sA, dAl + (size_t)t * 8);
    gl_lds16(Ph + sB, dBh + (size_t)t * 8);
    gl_lds16(Pl + sB, dBl + (size_t)t * 8);
  };

  const int rl = lane & 15, ch = lane >> 4;
  auto COMPUTE = [&](const _Float16* bAh, const _Float16* bAl,
                     const _Float16* bBh, const _Float16* bBl) {
    half8 ah[2], al[2], bh[2], bl[2];
#pragma unroll
    for (int m = 0; m < 2; ++m) {
      const int s = swz(wr * 32 + m * 16 + rl, ch);
      ah[m] = *(const half8*)&bAh[(size_t)s * 8];
      al[m] = *(const half8*)&bAl[(size_t)s * 8];
    }
#pragma unroll
    for (int n = 0; n < 2; ++n) {
      const int s = swz(wc * 32 + n * 16 + rl, ch);
      bh[n] = *(const half8*)&bBh[(size_t)s * 8];
      bl[n] = *(const half8*)&bBl[(size_t)s * 8];
    }
#pragma unroll
    for (int m = 0; m < 2; ++m)
#pragma unroll
      for (int n = 0; n < 2; ++n) {
        accH[m][n] = __builtin_amdgcn_mfma_f32_16x16x32_f16(ah[m], bh[n], accH[m][n], 0, 0, 0);
        accX[m][n] = __builtin_amdgcn_mfma_f32_16x16x32_f16(ah[m], bl[n], accX[m][n], 0, 0, 0);
        accX[m][n] = __builtin_amdgcn_mfma_f32_16x16x32_f16(al[m], bh[n], accX[m][n], 0, 0, 0);
      }
  };

  STAGE(sAh0, sAl0, sBh0, sBl0, 0);
  __syncthreads();
#pragma unroll 1
  for (int kt = 0; kt < NKT; kt += 2) {
    if (kt + 1 < NKT) STAGE(sAh1, sAl1, sBh1, sBl1, kt + 1);
    COMPUTE(sAh0, sAl0, sBh0, sBl0);
    __syncthreads();
    if (kt + 2 < NKT) STAGE(sAh0, sAl0, sBh0, sBl0, kt + 2);
    COMPUTE(sAh1, sAl1, sBh1, sBl1);
    __syncthreads();
  }

  // ---- fused epilogue; C/D layout (HW-verified): col=lane&15, row=(lane>>4)*4+reg ----
  const int colLane = lane & 15;
  const int rowLane = lane >> 4;
#pragma unroll
  for (int m = 0; m < 2; ++m) {
#pragma unroll
    for (int v = 0; v < 4; ++v) {
      const int ql = wr * 32 + m * 16 + rowLane * 4 + v;   // [0,64)
      const int q  = qb + ql;
      const float4 g0 = *(const float4*)&G[(size_t)q * 8];
      const float4 g1 = *(const float4*)&G[(size_t)q * 8 + 4];
      const float gv[8] = {g0.x, g0.y, g0.z, g0.w, g1.x, g1.y, g1.z, g1.w};
      const int qg = q >> 3;
      float sv[2];
      int jg[2], jp[2];
#pragma unroll
      for (int n = 0; n < 2; ++n) {
        sv[n] = accH[m][n][v] + accX[m][n][v] * INV_LO;
        const int j = jb + wc * 32 + n * 16 + colLane;
        jg[n] = j >> 3;
        jp[n] = j & 7;
      }
#pragma unroll
      for (int i = 0; i < 8; ++i) {
        float pr = 0.0f;
#pragma unroll
        for (int n = 0; n < 2; ++n) {
          float s = sig_fast(sv[n] - gv[i]);
          if (jg[n] == qg && jp[n] == i) s = 0.0f;   // exact diag exclusion
          pr += s;
        }
        pr += __shfl_xor(pr, 1);
        pr += __shfl_xor(pr, 2);
        pr += __shfl_xor(pr, 4);
        pr += __shfl_xor(pr, 8);
        if (colLane == 0) sRed[wc][ql][i] = pr;      // LDS, no global atomic
      }
    }
  }
  __syncthreads();
  // combine the two j-halves + ONE coalesced 2KB store per block
  if (t < 128) {
    const float* r0 = &sRed[0][0][0];
    const float* r1 = &sRed[1][0][0];
    float4 a = *(const float4*)&r0[t * 4];
    float4 b = *(const float4*)&r1[t * 4];
    float4 s = {a.x + b.x, a.y + b.y, a.z + b.z, a.w + b.w};
    *(float4*)&partial[((size_t)jbIdx * BATCH + qb) * SPC + t * 4] = s;
  }
}

// ---------------- kernel 2: reduce partials -> rank -> recall -> scalar loss ----------------
// one thread per (q,i): 64 blocks, coalesced reads, shfl-reduce over the 8 i-lanes.
__global__ __launch_bounds__(256) void k_fin(const float* __restrict__ partial,
                                             float* __restrict__ out) {
  const int tg = blockIdx.x * 256 + threadIdx.x;     // [0, 16384) <-> (q = tg>>3, i = tg&7)
  const int q = tg >> 3, i = tg & 7;
  float rk = 1.0f;
#pragma unroll 8
  for (int p = 0; p < NJB; ++p)
    rk += partial[(size_t)p * BATCH * SPC + tg];     // (p*BATCH+q)*8+i == p*B*8+tg, coalesced
  const float kv[5]  = {1.f, 2.f, 4.f, 8.f, 16.f};
  const float rkt[5] = {1.f, 0.5f, 0.25f, 0.125f, 0.0625f};
  const float nv[5]  = {1.f, 2.f, 4.f, 7.f, 7.f};
  const bool self = (i == (q & 7));
  float vs[5];
#pragma unroll
  for (int k = 0; k < 5; ++k) {
    float e = (rk - kv[k]) * rkt[k];
    e = fminf(fmaxf(e, -50.0f), 50.0f);
    float v = 1.0f / (1.0f + __expf(e));
    vs[k] = self ? 0.0f : v;
  }
#pragma unroll
  for (int o = 1; o < 8; o <<= 1)
#pragma unroll
    for (int k = 0; k < 5; ++k) vs[k] += __shfl_xor(vs[k], o);
  float tv = 0.0f;
  if (i == 0) {
    float rq = 0.0f;
#pragma unroll
    for (int k = 0; k < 5; ++k) rq += fminf(vs[k], kv[k]) / nv[k];
    tv = (1.0f - rq * 0.2f) * (1.0f / (float)BATCH);
  }
#pragma unroll
  for (int o = 1; o < 64; o <<= 1) tv += __shfl_xor(tv, o);
  __shared__ float sw[4];
  if ((threadIdx.x & 63) == 0) sw[threadIdx.x >> 6] = tv;
  __syncthreads();
  if (threadIdx.x == 0) atomicAdd(out, sw[0] + sw[1] + sw[2] + sw[3]);
}

extern "C" void kernel_launch(void* const* d_in, const int* in_sizes, int n_in,
                              void* d_out, int out_size, void* d_ws, size_t ws_size,
                              hipStream_t stream) {
  const float* preds = (const float*)d_in[0];
  float* G       = (float*)d_ws;                                      // 64 KB
  float* partial = (float*)((char*)d_ws + (64 << 10));                // 2 MB [NJB][BATCH][SPC]
  _Float16* Ph   = (_Float16*)((char*)d_ws + (64 << 10) + (2 << 20)); // 4 MB
  _Float16* Pl   = Ph + (size_t)BATCH * DIM;                          // 4 MB (ws >= ~10.1 MB)
  hipMemsetAsync(d_out, 0, sizeof(float), stream);
  k_prep<<<BATCH + BATCH / SPC, 256, 0, stream>>>(preds, Ph, Pl, G);
  k_main<<<dim3(32, 32), 256, 0, stream>>>(Ph, Pl, G, partial);
  k_fin<<<64, 256, 0, stream>>>(partial, (float*)d_out);
}

// Round 9
// 119.351 us; speedup vs baseline: 1.9961x; 1.0188x over previous
//
#include <hip/hip_runtime.h>

#define BATCH 2048
#define DIM   1024
#define SPC   8
#define BM    64
#define BN    64
#define BK    32
#define NKT   (DIM / BK)   // 32

typedef _Float16 half8 __attribute__((ext_vector_type(8)));
typedef float    f32x4 __attribute__((ext_vector_type(4)));

constexpr float INV_T    = 1.0f / 0.01f;
constexpr float LO_SCALE = 2048.0f;        // 2^11, exact
constexpr float INV_LO   = 1.0f / 2048.0f;

__device__ __forceinline__ float sig_fast(float x) {
  // e = clip(-x/0.01, -50, 50); 1/(1+exp(e)) with v_rcp (absmax 0.0 in R8)
  float e = fminf(fmaxf(-x * INV_T, -50.0f), 50.0f);
  return __builtin_amdgcn_rcpf(1.0f + __expf(e));
}

// bank-conflict-free swizzle (verified R5/R8: SQ_LDS_BANK_CONFLICT ~0 on staging)
__device__ __forceinline__ int swz(int row, int c) { return row * 4 + (c ^ ((row >> 1) & 3)); }

// ---------------- kernel 1: reg-staged split-fp16 MFMA GEMM -> S (materialized) ----------
// On-the-fly fp32->h/l split (no Ph/Pl workspace, no split kernel). 64x64 tiles, 1024 blocks.
template <bool S16>
__global__ __launch_bounds__(256, 4) void k_gemm(const float* __restrict__ P,
                                                 void* __restrict__ Sout,
                                                 float* __restrict__ out0) {
  __shared__ __align__(16) char LDSBUF[32768];
  _Float16* sAh0 = (_Float16*)(LDSBUF);
  _Float16* sAl0 = (_Float16*)(LDSBUF + 4096);
  _Float16* sBh0 = (_Float16*)(LDSBUF + 8192);
  _Float16* sBl0 = (_Float16*)(LDSBUF + 12288);
  _Float16* sAh1 = (_Float16*)(LDSBUF + 16384);
  _Float16* sAl1 = (_Float16*)(LDSBUF + 20480);
  _Float16* sBh1 = (_Float16*)(LDSBUF + 24576);
  _Float16* sBl1 = (_Float16*)(LDSBUF + 28672);

  const int t    = threadIdx.x;
  const int lane = t & 63;
  const int w    = t >> 6;
  const int wr   = w >> 1, wc = w & 1;        // 2x2 waves, 32x32 tile each

  const int d = blockIdx.y * 32 + blockIdx.x;
  if (d == 0 && t == 0) *out0 = 0.0f;          // d_out init (k_loss runs strictly after)
  // XCD mapping (R8-verified): xcd owns 4 j-tiles -> B-panel L2-resident
  const int xcd = d & 7, idx = d >> 3;
  const int jbIdx = xcd * 4 + (idx & 3);
  const int qb = (idx >> 2) * BM;
  const int jb = jbIdx * BN;

  f32x4 accH[2][2], accX[2][2];
#pragma unroll
  for (int m = 0; m < 2; ++m)
#pragma unroll
    for (int n = 0; n < 2; ++n) {
      accH[m][n] = (f32x4){0.f, 0.f, 0.f, 0.f};
      accX[m][n] = (f32x4){0.f, 0.f, 0.f, 0.f};
    }

  const int srow  = t >> 2;                    // 0..63
  const int sc    = t & 3;                     // 16B-slot col (8 fp16)
  const int wslot = swz(srow, sc);

  f32x4 rA0, rA1, rB0, rB1;                    // staged fp32 regs (issued early, T14)
  auto LOADREGS = [&](int kt) {
    const float* pa = P + (size_t)(qb + srow) * DIM + kt * BK + sc * 8;
    const float* pb = P + (size_t)(jb + srow) * DIM + kt * BK + sc * 8;
    rA0 = *(const f32x4*)pa; rA1 = *(const f32x4*)(pa + 4);
    rB0 = *(const f32x4*)pb; rB1 = *(const f32x4*)(pb + 4);
  };
  auto SPLITW = [&](_Float16* dAh, _Float16* dAl, _Float16* dBh, _Float16* dBl) {
    half8 h, l;
    {
      float xs[8] = {rA0[0], rA0[1], rA0[2], rA0[3], rA1[0], rA1[1], rA1[2], rA1[3]};
#pragma unroll
      for (int e = 0; e < 8; ++e) {
        h[e] = (_Float16)xs[e];
        l[e] = (_Float16)((xs[e] - (float)h[e]) * LO_SCALE);
      }
      *(half8*)&dAh[wslot * 8] = h;
      *(half8*)&dAl[wslot * 8] = l;
    }
    {
      float xs[8] = {rB0[0], rB0[1], rB0[2], rB0[3], rB1[0], rB1[1], rB1[2], rB1[3]};
#pragma unroll
      for (int e = 0; e < 8; ++e) {
        h[e] = (_Float16)xs[e];
        l[e] = (_Float16)((xs[e] - (float)h[e]) * LO_SCALE);
      }
      *(half8*)&dBh[wslot * 8] = h;
      *(half8*)&dBl[wslot * 8] = l;
    }
  };

  const int rl = lane & 15, ch = lane >> 4;
  auto COMPUTE = [&](const _Float16* bAh, const _Float16* bAl,
                     const _Float16* bBh, const _Float16* bBl) {
    half8 ah[2], al[2], bh[2], bl[2];
#pragma unroll
    for (int m = 0; m < 2; ++m) {
      const int s = swz(wr * 32 + m * 16 + rl, ch);
      ah[m] = *(const half8*)&bAh[(size_t)s * 8];
      al[m] = *(const half8*)&bAl[(size_t)s * 8];
    }
#pragma unroll
    for (int n = 0; n < 2; ++n) {
      const int s = swz(wc * 32 + n * 16 + rl, ch);
      bh[n] = *(const half8*)&bBh[(size_t)s * 8];
      bl[n] = *(const half8*)&bBl[(size_t)s * 8];
    }
#pragma unroll
    for (int m = 0; m < 2; ++m)
#pragma unroll
      for (int n = 0; n < 2; ++n) {
        accH[m][n] = __builtin_amdgcn_mfma_f32_16x16x32_f16(ah[m], bh[n], accH[m][n], 0, 0, 0);
        accX[m][n] = __builtin_amdgcn_mfma_f32_16x16x32_f16(ah[m], bl[n], accX[m][n], 0, 0, 0);
        accX[m][n] = __builtin_amdgcn_mfma_f32_16x16x32_f16(al[m], bh[n], accX[m][n], 0, 0, 0);
      }
  };

  LOADREGS(0);
  SPLITW(sAh0, sAl0, sBh0, sBl0);
  LOADREGS(1);
  __syncthreads();
#pragma unroll 1
  for (int kt = 0; kt < NKT; kt += 2) {
    COMPUTE(sAh0, sAl0, sBh0, sBl0);
    SPLITW(sAh1, sAl1, sBh1, sBl1);            // regs hold kt+1; disjoint buffer, no barrier needed
    if (kt + 2 < NKT) LOADREGS(kt + 2);
    __syncthreads();
    COMPUTE(sAh1, sAl1, sBh1, sBl1);
    if (kt + 2 < NKT) {
      SPLITW(sAh0, sAl0, sBh0, sBl0);
      if (kt + 3 < NKT) LOADREGS(kt + 3);
    }
    __syncthreads();
  }

  // ---- epilogue: acc -> LDS tile (reuse staging LDS) -> coalesced S store ----
  // C/D layout (HW-verified): col=lane&15, row=(lane>>4)*4+reg
  float* stile = (float*)LDSBUF;               // [64][68] padded, 17408 B
  const int colL = lane & 15, rowL = lane >> 4;
#pragma unroll
  for (int m = 0; m < 2; ++m)
#pragma unroll
    for (int n = 0; n < 2; ++n)
#pragma unroll
      for (int v = 0; v < 4; ++v) {
        const int r = wr * 32 + m * 16 + rowL * 4 + v;
        const int c = wc * 32 + n * 16 + colL;
        stile[r * 68 + c] = accH[m][n][v] + accX[m][n][v] * INV_LO;
      }
  __syncthreads();
  {
    const int row = t >> 2, c4 = t & 3;        // 16 floats per thread, coalesced rows
    const float* src = &stile[row * 68 + c4 * 16];
    if (S16) {
      _Float16* S = (_Float16*)Sout + (size_t)(qb + row) * BATCH + jb + c4 * 16;
      half8 h0, h1;
#pragma unroll
      for (int e = 0; e < 8; ++e) { h0[e] = (_Float16)src[e]; h1[e] = (_Float16)src[8 + e]; }
      *(half8*)S = h0;
      *(half8*)(S + 8) = h1;
    } else {
      float* S = (float*)Sout + (size_t)(qb + row) * BATCH + jb + c4 * 16;
      f32x4 v0 = *(const f32x4*)(src);
      f32x4 v1 = *(const f32x4*)(src + 4);
      f32x4 v2 = *(const f32x4*)(src + 8);
      f32x4 v3 = *(const f32x4*)(src + 12);
      *(f32x4*)(S)      = v0;
      *(f32x4*)(S + 4)  = v1;
      *(f32x4*)(S + 8)  = v2;
      *(f32x4*)(S + 12) = v3;
    }
  }
}

// ---------------- kernel 2: S -> sigmoid ranks -> recall -> scalar loss ----------------
// 512 blocks x 4 waves; each wave owns one q-row: j per-thread serial (in-register
// reduction, no shuffle storm), G[q][i] = S[q, (q>>3)*8+i] read directly from S.
template <bool S16>
__global__ __launch_bounds__(256) void k_loss(const void* __restrict__ Sv,
                                              float* __restrict__ out) {
  const int w = threadIdx.x >> 6, lane = threadIdx.x & 63;
  const int q = blockIdx.x * 4 + w;
  const int qg = q >> 3;
  const float* Sf = (const float*)Sv;
  const _Float16* Sh = (const _Float16*)Sv;

  float gv[8];
#pragma unroll
  for (int i = 0; i < 8; ++i)
    gv[i] = S16 ? (float)Sh[(size_t)q * BATCH + qg * 8 + i]
                : Sf[(size_t)q * BATCH + qg * 8 + i];

  float acc[8] = {0.f, 0.f, 0.f, 0.f, 0.f, 0.f, 0.f, 0.f};
#pragma unroll 4
  for (int jj = 0; jj < 32; ++jj) {
    const int j = jj * 64 + lane;              // coalesced 256B per wave
    const float s = S16 ? (float)Sh[(size_t)q * BATCH + j] : Sf[(size_t)q * BATCH + j];
    const int ex = ((j >> 3) == qg) ? (j & 7) : -1;   // diag exclusion j == qg*8+i
#pragma unroll
    for (int i = 0; i < 8; ++i) {
      float v = sig_fast(s - gv[i]);
      acc[i] += (i == ex) ? 0.0f : v;
    }
  }
#pragma unroll
  for (int o = 1; o < 64; o <<= 1)
#pragma unroll
    for (int i = 0; i < 8; ++i) acc[i] += __shfl_xor(acc[i], o);

  float tv = 0.0f;
  if (lane == 0) {
    const float kv[5]  = {1.f, 2.f, 4.f, 8.f, 16.f};
    const float rkt[5] = {1.f, 0.5f, 0.25f, 0.125f, 0.0625f};  // 1/k_temp, exact pow2
    const float nv[5]  = {1.f, 2.f, 4.f, 7.f, 7.f};            // min(k, spc-1)
    const int r = q & 7;
    float rq = 0.0f;
#pragma unroll
    for (int k = 0; k < 5; ++k) {
      float vs = 0.0f;
#pragma unroll
      for (int i = 0; i < 8; ++i) {
        const float rk = 1.0f + acc[i];
        float e = fminf(fmaxf((rk - kv[k]) * rkt[k], -50.0f), 50.0f);
        float v = 1.0f / (1.0f + __expf(e));
        vs += (i == r) ? 0.0f : v;             // self_mask
      }
      rq += fminf(vs, kv[k]) / nv[k];
    }
    tv = (1.0f - rq * 0.2f) * (1.0f / (float)BATCH);
  }
  __shared__ float sw[4];
  if (lane == 0) sw[w] = tv;
  __syncthreads();
  if (threadIdx.x == 0) atomicAdd(out, sw[0] + sw[1] + sw[2] + sw[3]);
}

extern "C" void kernel_launch(void* const* d_in, const int* in_sizes, int n_in,
                              void* d_out, int out_size, void* d_ws, size_t ws_size,
                              hipStream_t stream) {
  const float* preds = (const float*)d_in[0];
  float* out = (float*)d_out;
  // Hedge: fp32 S needs 16.78 MB of ws; fall back to fp16 S if ws is smaller.
  // ws_size is constant across calls -> same path every launch (graph-safe).
  if (ws_size >= (size_t)BATCH * BATCH * sizeof(float)) {
    k_gemm<false><<<dim3(32, 32), 256, 0, stream>>>(preds, d_ws, out);
    k_loss<false><<<BATCH / 4, 256, 0, stream>>>(d_ws, out);
  } else {
    k_gemm<true><<<dim3(32, 32), 256, 0, stream>>>(preds, d_ws, out);
    k_loss<true><<<BATCH / 4, 256, 0, stream>>>(d_ws, out);
  }
}